// Round 12
// baseline (1050.633 us; speedup 1.0000x reference)
//
#include <hip/hip_runtime.h>
#include <hip/hip_bf16.h>
#include <stdint.h>

#define BB 8
#define NN 65536
#define CIN 64
#define COUT 128
#define NT (BB*NN)
#define GRIDSZ 0.05f
#define VOXCAP 16384
#define EPSBN 1e-5f

// monotone float<->uint encoding for atomicMax on floats (handles negatives)
__device__ __forceinline__ unsigned int encf(float f) {
  unsigned int u = __float_as_uint(f);
  return (u & 0x80000000u) ? ~u : (u | 0x80000000u);
}
__device__ __forceinline__ float decf(unsigned int u) {
  unsigned int v = (u & 0x80000000u) ? (u ^ 0x80000000u) : ~u;
  return __uint_as_float(v);
}

// -------- per-batch xyz min (atomicMin on raw bits; coords >= 0) --------
__global__ __launch_bounds__(256) void k_min(const float* __restrict__ xyz,
                                             unsigned int* __restrict__ mins) {
  int b = blockIdx.x >> 6;       // 64 blocks per batch
  int chunk = blockIdx.x & 63;   // 1024 points per block
  int tid = threadIdx.x;
  float mn0 = 3.4e38f, mn1 = 3.4e38f, mn2 = 3.4e38f;
  size_t base = ((size_t)b * NN + (size_t)chunk * 1024) * 3;
  for (int j = 0; j < 4; ++j) {
    int p = j * 256 + tid;
    float x = xyz[base + 3*p + 0];
    float y = xyz[base + 3*p + 1];
    float z = xyz[base + 3*p + 2];
    mn0 = fminf(mn0, x); mn1 = fminf(mn1, y); mn2 = fminf(mn2, z);
  }
  for (int off = 32; off; off >>= 1) {
    mn0 = fminf(mn0, __shfl_down(mn0, off));
    mn1 = fminf(mn1, __shfl_down(mn1, off));
    mn2 = fminf(mn2, __shfl_down(mn2, off));
  }
  if ((tid & 63) == 0) {
    atomicMin(&mins[b*3+0], __float_as_uint(mn0));
    atomicMin(&mins[b*3+1], __float_as_uint(mn1));
    atomicMin(&mins[b*3+2], __float_as_uint(mn2));
  }
}

// -------- per-batch voxel-coord max --------
__global__ __launch_bounds__(256) void k_vmax(const float* __restrict__ xyz,
                                              const unsigned int* __restrict__ mins,
                                              int* __restrict__ vmax) {
  int b = blockIdx.x >> 6;
  int chunk = blockIdx.x & 63;
  int tid = threadIdx.x;
  float mn0 = __uint_as_float(mins[b*3+0]);
  float mn1 = __uint_as_float(mins[b*3+1]);
  float mn2 = __uint_as_float(mins[b*3+2]);
  int a0 = 0, a1 = 0, a2 = 0;
  size_t base = ((size_t)b * NN + (size_t)chunk * 1024) * 3;
  for (int j = 0; j < 4; ++j) {
    int p = j * 256 + tid;
    int v0 = (int)floorf((xyz[base + 3*p + 0] - mn0) / GRIDSZ);
    int v1 = (int)floorf((xyz[base + 3*p + 1] - mn1) / GRIDSZ);
    int v2 = (int)floorf((xyz[base + 3*p + 2] - mn2) / GRIDSZ);
    a0 = max(a0, v0); a1 = max(a1, v1); a2 = max(a2, v2);
  }
  for (int off = 32; off; off >>= 1) {
    a0 = max(a0, __shfl_down(a0, off));
    a1 = max(a1, __shfl_down(a1, off));
    a2 = max(a2, __shfl_down(a2, off));
  }
  if ((tid & 63) == 0) {
    atomicMax(&vmax[b*3+0], a0);
    atomicMax(&vmax[b*3+1], a1);
    atomicMax(&vmax[b*3+2], a2);
  }
}

// -------- vid per point + voxel counts + xyz sums --------
__global__ __launch_bounds__(256) void k_vid(const float* __restrict__ xyz,
                                             const unsigned int* __restrict__ mins,
                                             const int* __restrict__ vmax,
                                             int* __restrict__ vid,
                                             int* __restrict__ cnt,
                                             float* __restrict__ psum) {
  int gt = blockIdx.x * 256 + threadIdx.x;   // < NT
  int b = gt >> 16;
  size_t pbase = (size_t)gt * 3;
  float x = xyz[pbase + 0], y = xyz[pbase + 1], z = xyz[pbase + 2];
  float mn0 = __uint_as_float(mins[b*3+0]);
  float mn1 = __uint_as_float(mins[b*3+1]);
  float mn2 = __uint_as_float(mins[b*3+2]);
  int v0 = (int)floorf((x - mn0) / GRIDSZ);
  int v1 = (int)floorf((y - mn1) / GRIDSZ);
  int v2 = (int)floorf((z - mn2) / GRIDSZ);
  int mx1 = vmax[b*3+1] + 1, mx2 = vmax[b*3+2] + 1;
  int vd = (v0 * mx1 + v1) * mx2 + v2;
  vid[gt] = vd;
  int idx = b * VOXCAP + vd;
  atomicAdd(&cnt[idx], 1);
  atomicAdd(&psum[3*idx+0], x);
  atomicAdd(&psum[3*idx+1], y);
  atomicAdd(&psum[3*idx+2], z);
}

// -------- per-batch scan: occupied-voxel rank (= sorted-unique inverse) --------
__global__ __launch_bounds__(1024) void k_scan(const int* __restrict__ cnt,
                                               int* __restrict__ rank,
                                               int* __restrict__ cvox) {
  __shared__ int part[1024];
  int b = blockIdx.x, t = threadIdx.x;
  int base = b * VOXCAP + t * 16;
  int flags[16]; int c = 0;
  for (int i = 0; i < 16; ++i) { flags[i] = cnt[base+i] > 0; c += flags[i]; }
  part[t] = c;
  __syncthreads();
  for (int off = 1; off < 1024; off <<= 1) {
    int v = (t >= off) ? part[t-off] : 0;
    __syncthreads();
    part[t] += v;
    __syncthreads();
  }
  int r = part[t] - c;  // exclusive prefix
  for (int i = 0; i < 16; ++i) {
    if (flags[i]) {
      rank[base+i] = r;
      cvox[b * VOXCAP + r] = t*16 + i;
      ++r;
    }
  }
}

// -------- fused GEMM (fp32) + BN-stat accumulation + raw-h atomicMax pooling --------
// 128 pts x 128 ch tile per block of 256 threads; thread tile 8x8.
// BN(scale>0)+ReLU commute with max => pool raw h, apply affine+relu in finalize.
// pool aliases the pooled-features region of d_out (encoded uints, finalized in place).
__global__ __launch_bounds__(256) void k_gemm_pool(
    const float* __restrict__ feats, const float* __restrict__ Wg,
    const float* __restrict__ bias,
    const int* __restrict__ vid, const int* __restrict__ rank,
    unsigned int* __restrict__ pool, float* __restrict__ stats, int m)
{
  __shared__ float4 sF4[128*17];   // [pt][k/4], padded 16->17 to spread banks
  __shared__ float4 sW4[2048];     // [k][c/4] row-major 64x128
  __shared__ int r_loc[128];
  __shared__ float sh_sum[128], sh_sq[128];
  int tid = threadIdx.x;
  int blk = blockIdx.x;
  int b = blk >> 9;                // 512 blocks per batch
  const float4* F4 = (const float4*)feats + (size_t)blk * 2048;
  const float4* W4 = (const float4*)Wg;
  #pragma unroll
  for (int t = 0; t < 8; ++t) {
    int idx = t*256 + tid;
    sW4[idx] = W4[idx];
    float4 v = F4[idx];
    int row = idx >> 4, q = idx & 15;
    sF4[row*17 + q] = v;
  }
  if (tid < 128) {
    int v = vid[blk*128 + tid];
    r_loc[tid] = rank[b * VOXCAP + v];
    sh_sum[tid] = 0.f; sh_sq[tid] = 0.f;
  }
  __syncthreads();

  int tp = tid & 15, tc = tid >> 4;
  float acc[8][8];
  #pragma unroll
  for (int i = 0; i < 8; ++i)
    #pragma unroll
    for (int j = 0; j < 8; ++j) acc[i][j] = 0.f;

  for (int k4 = 0; k4 < 16; ++k4) {
    float wlo[4][4], whi[4][4];
    #pragma unroll
    for (int e = 0; e < 4; ++e) {
      float4 t0 = sW4[(4*k4+e)*32 + tc];
      float4 t1 = sW4[(4*k4+e)*32 + 16 + tc];
      wlo[e][0]=t0.x; wlo[e][1]=t0.y; wlo[e][2]=t0.z; wlo[e][3]=t0.w;
      whi[e][0]=t1.x; whi[e][1]=t1.y; whi[e][2]=t1.z; whi[e][3]=t1.w;
    }
    #pragma unroll
    for (int pj = 0; pj < 8; ++pj) {
      int p = (pj < 4) ? (4*tp + pj) : (60 + 4*tp + pj);  // {4tp..+3} U {64+4tp..+3}
      float4 fv = sF4[p*17 + k4];
      float fe[4] = {fv.x, fv.y, fv.z, fv.w};
      #pragma unroll
      for (int e = 0; e < 4; ++e) {
        #pragma unroll
        for (int c = 0; c < 4; ++c) {
          acc[pj][c]   += fe[e] * wlo[e][c];
          acc[pj][4+c] += fe[e] * whi[e][c];
        }
      }
    }
  }

  int clo = 4*tc, chi = 64 + 4*tc;
  float bl[4], bh[4];
  #pragma unroll
  for (int c = 0; c < 4; ++c) { bl[c] = bias[clo+c]; bh[c] = bias[chi+c]; }
  #pragma unroll
  for (int pj = 0; pj < 8; ++pj)
    #pragma unroll
    for (int c = 0; c < 4; ++c) { acc[pj][c] += bl[c]; acc[pj][4+c] += bh[c]; }

  // stats partials (raw h, pre-ReLU/pre-BN)
  #pragma unroll
  for (int c = 0; c < 4; ++c) {
    float s0=0.f, q0=0.f, s1=0.f, q1=0.f;
    #pragma unroll
    for (int pj = 0; pj < 8; ++pj) {
      float a = acc[pj][c], d = acc[pj][4+c];
      s0 += a; q0 += a*a; s1 += d; q1 += d*d;
    }
    atomicAdd(&sh_sum[clo+c], s0); atomicAdd(&sh_sq[clo+c], q0);
    atomicAdd(&sh_sum[chi+c], s1); atomicAdd(&sh_sq[chi+c], q1);
  }

  // pooling: atomicMax of encoded raw h into [b, r, c].
  // Read-test-skip first: pool values are monotonically increasing and any
  // (possibly stale) cached read is a previously-committed value, so skipping
  // when cur >= cand is race-safe and cuts atomic traffic ~3.5x.
  size_t poolbase = (size_t)b * m * COUT;
  #pragma unroll
  for (int pj = 0; pj < 8; ++pj) {
    int p = (pj < 4) ? (4*tp + pj) : (60 + 4*tp + pj);
    int r = r_loc[p];
    if (r < m) {
      unsigned int* pp = pool + poolbase + (size_t)r * COUT;
      #pragma unroll
      for (int c = 0; c < 4; ++c) {
        unsigned int e0 = encf(acc[pj][c]);
        unsigned int e1 = encf(acc[pj][4+c]);
        if (pp[clo+c] < e0) atomicMax(&pp[clo+c], e0);
        if (pp[chi+c] < e1) atomicMax(&pp[chi+c], e1);
      }
    }
  }

  __syncthreads();
  if (tid < 128) {
    atomicAdd(&stats[tid], sh_sum[tid]);
    atomicAdd(&stats[128+tid], sh_sq[tid]);
  }
}

// -------- finalize: points mean + BN(affine)+ReLU on pooled maxima (in place) --------
__global__ __launch_bounds__(256) void k_finalize(
    const float* __restrict__ psum, const int* __restrict__ cnt,
    const int* __restrict__ cvox, const float* __restrict__ stats,
    const float* __restrict__ gamma, const float* __restrict__ beta,
    float* __restrict__ out, int m)
{
  int idx = blockIdx.x * 256 + threadIdx.x;
  int npts = BB * m * 3;
  int total = npts + BB * m * COUT;
  if (idx >= total) return;
  if (idx < npts) {
    int b = idx / (m*3); int rem = idx - b*m*3; int r = rem/3, d = rem - 3*r;
    int vox = cvox[b * VOXCAP + r];
    int ii = b * VOXCAP + vox;
    out[idx] = psum[3*ii + d] / (float)cnt[ii];
  } else {
    int c = (idx - npts) & 127;
    float s1 = stats[c], s2 = stats[128+c];
    float mu = s1 / (float)NT;
    float var = s2 / (float)NT - mu*mu;
    float scale = gamma[c] * (1.0f / sqrtf(var + EPSBN));
    float shift = beta[c] - mu * scale;
    // out[idx] currently holds the encoded-uint max; decode and finalize in place.
    float v = decf(__float_as_uint(out[idx]));
    out[idx] = fmaxf(v * scale + shift, 0.f);
  }
}

extern "C" void kernel_launch(void* const* d_in, const int* in_sizes, int n_in,
                              void* d_out, int out_size, void* d_ws, size_t ws_size,
                              hipStream_t stream) {
  const float* xyz   = (const float*)d_in[0];
  const float* feats = (const float*)d_in[1];
  const float* Wg    = (const float*)d_in[2];
  const float* bias  = (const float*)d_in[3];
  const float* gamma = (const float*)d_in[4];
  const float* beta  = (const float*)d_in[5];
  float* out = (float*)d_out;
  int m = out_size / (BB * (3 + COUT));
  if (m <= 0) return;
  int npts = BB * m * 3;
  unsigned int* pool = (unsigned int*)(out + npts);   // pooled-features region of d_out

  char* ws = (char*)d_ws;
  size_t off = 0;
  auto alloc = [&](size_t bytes) { void* p = ws + off; off += (bytes + 255) & ~255ull; return p; };
  unsigned int* mins = (unsigned int*)alloc(BB*3*4);
  size_t zstart = off;
  int*   vmax = (int*)alloc(BB*3*4);
  int*   cnt  = (int*)alloc((size_t)BB*VOXCAP*4);
  float* psum = (float*)alloc((size_t)BB*VOXCAP*3*4);
  float* stats= (float*)alloc(2*COUT*4);
  size_t zend = off;
  int*   vid  = (int*)alloc((size_t)NT*4);
  int*   rank = (int*)alloc((size_t)BB*VOXCAP*4);
  int*   cvox = (int*)alloc((size_t)BB*VOXCAP*4);
  if (off > ws_size) return;  // ~5.3 MB needed; output stays poisoned if insufficient

  hipMemsetAsync(mins, 0x7F, 96, stream);                     // ~3.39e38 per word
  hipMemsetAsync(ws + zstart, 0, zend - zstart, stream);
  hipMemsetAsync(pool, 0, (size_t)BB*m*COUT*4, stream);       // encf(x)>0 ∀x, so 0 = -inf sentinel

  k_min  <<<BB*64, 256, 0, stream>>>(xyz, mins);
  k_vmax <<<BB*64, 256, 0, stream>>>(xyz, mins, vmax);
  k_vid  <<<NT/256, 256, 0, stream>>>(xyz, mins, vmax, vid, cnt, psum);
  k_scan <<<BB, 1024, 0, stream>>>(cnt, rank, cvox);
  k_gemm_pool<<<NT/128, 256, 0, stream>>>(feats, Wg, bias, vid, rank, pool, stats, m);
  int total = npts + BB*m*COUT;
  k_finalize<<<(total + 255)/256, 256, 0, stream>>>(psum, cnt, cvox, stats, gamma, beta, out, m);
}

// Round 13
// 706.900 us; speedup vs baseline: 1.4863x; 1.4863x over previous
//
#include <hip/hip_runtime.h>
#include <hip/hip_bf16.h>
#include <stdint.h>

#define BB 8
#define NN 65536
#define CIN 64
#define COUT 128
#define NT (BB*NN)
#define GRIDSZ 0.05f
#define VOXCAP 16384
#define EPSBN 1e-5f

// monotone float<->uint encoding for atomicMax on floats (handles negatives)
__device__ __forceinline__ unsigned int encf(float f) {
  unsigned int u = __float_as_uint(f);
  return (u & 0x80000000u) ? ~u : (u | 0x80000000u);
}
__device__ __forceinline__ float decf(unsigned int u) {
  unsigned int v = (u & 0x80000000u) ? (u ^ 0x80000000u) : ~u;
  return __uint_as_float(v);
}

// -------- per-batch xyz min (atomicMin on raw bits; coords >= 0) --------
__global__ __launch_bounds__(256) void k_min(const float* __restrict__ xyz,
                                             unsigned int* __restrict__ mins) {
  int b = blockIdx.x >> 6;
  int chunk = blockIdx.x & 63;
  int tid = threadIdx.x;
  float mn0 = 3.4e38f, mn1 = 3.4e38f, mn2 = 3.4e38f;
  size_t base = ((size_t)b * NN + (size_t)chunk * 1024) * 3;
  for (int j = 0; j < 4; ++j) {
    int p = j * 256 + tid;
    float x = xyz[base + 3*p + 0];
    float y = xyz[base + 3*p + 1];
    float z = xyz[base + 3*p + 2];
    mn0 = fminf(mn0, x); mn1 = fminf(mn1, y); mn2 = fminf(mn2, z);
  }
  for (int off = 32; off; off >>= 1) {
    mn0 = fminf(mn0, __shfl_down(mn0, off));
    mn1 = fminf(mn1, __shfl_down(mn1, off));
    mn2 = fminf(mn2, __shfl_down(mn2, off));
  }
  if ((tid & 63) == 0) {
    atomicMin(&mins[b*3+0], __float_as_uint(mn0));
    atomicMin(&mins[b*3+1], __float_as_uint(mn1));
    atomicMin(&mins[b*3+2], __float_as_uint(mn2));
  }
}

// -------- per-batch voxel-coord max --------
__global__ __launch_bounds__(256) void k_vmax(const float* __restrict__ xyz,
                                              const unsigned int* __restrict__ mins,
                                              int* __restrict__ vmax) {
  int b = blockIdx.x >> 6;
  int chunk = blockIdx.x & 63;
  int tid = threadIdx.x;
  float mn0 = __uint_as_float(mins[b*3+0]);
  float mn1 = __uint_as_float(mins[b*3+1]);
  float mn2 = __uint_as_float(mins[b*3+2]);
  int a0 = 0, a1 = 0, a2 = 0;
  size_t base = ((size_t)b * NN + (size_t)chunk * 1024) * 3;
  for (int j = 0; j < 4; ++j) {
    int p = j * 256 + tid;
    int v0 = (int)floorf((xyz[base + 3*p + 0] - mn0) / GRIDSZ);
    int v1 = (int)floorf((xyz[base + 3*p + 1] - mn1) / GRIDSZ);
    int v2 = (int)floorf((xyz[base + 3*p + 2] - mn2) / GRIDSZ);
    a0 = max(a0, v0); a1 = max(a1, v1); a2 = max(a2, v2);
  }
  for (int off = 32; off; off >>= 1) {
    a0 = max(a0, __shfl_down(a0, off));
    a1 = max(a1, __shfl_down(a1, off));
    a2 = max(a2, __shfl_down(a2, off));
  }
  if ((tid & 63) == 0) {
    atomicMax(&vmax[b*3+0], a0);
    atomicMax(&vmax[b*3+1], a1);
    atomicMax(&vmax[b*3+2], a2);
  }
}

// -------- vid per point + voxel counts + xyz sums --------
__global__ __launch_bounds__(256) void k_vid(const float* __restrict__ xyz,
                                             const unsigned int* __restrict__ mins,
                                             const int* __restrict__ vmax,
                                             int* __restrict__ vid,
                                             int* __restrict__ cnt,
                                             float* __restrict__ psum) {
  int gt = blockIdx.x * 256 + threadIdx.x;
  int b = gt >> 16;
  size_t pbase = (size_t)gt * 3;
  float x = xyz[pbase + 0], y = xyz[pbase + 1], z = xyz[pbase + 2];
  float mn0 = __uint_as_float(mins[b*3+0]);
  float mn1 = __uint_as_float(mins[b*3+1]);
  float mn2 = __uint_as_float(mins[b*3+2]);
  int v0 = (int)floorf((x - mn0) / GRIDSZ);
  int v1 = (int)floorf((y - mn1) / GRIDSZ);
  int v2 = (int)floorf((z - mn2) / GRIDSZ);
  int mx1 = vmax[b*3+1] + 1, mx2 = vmax[b*3+2] + 1;
  int vd = (v0 * mx1 + v1) * mx2 + v2;
  vid[gt] = vd;
  int idx = b * VOXCAP + vd;
  atomicAdd(&cnt[idx], 1);
  atomicAdd(&psum[3*idx+0], x);
  atomicAdd(&psum[3*idx+1], y);
  atomicAdd(&psum[3*idx+2], z);
}

// -------- per-batch dual scan: voxel rank + point-offset prefix --------
__global__ __launch_bounds__(1024) void k_scan(const int* __restrict__ cnt,
                                               int* __restrict__ rank,
                                               int* __restrict__ cvox,
                                               int* __restrict__ pbase) {
  __shared__ int partA[1024];  // occupied-voxel counts
  __shared__ int partB[1024];  // point counts
  int b = blockIdx.x, t = threadIdx.x;
  int base = b * VOXCAP + t * 16;
  int cs[16]; int flags[16]; int cA = 0, cB = 0;
  for (int i = 0; i < 16; ++i) {
    int cv = cnt[base+i];
    cs[i] = cv; flags[i] = cv > 0; cA += flags[i]; cB += cv;
  }
  partA[t] = cA; partB[t] = cB;
  __syncthreads();
  for (int off = 1; off < 1024; off <<= 1) {
    int vA = (t >= off) ? partA[t-off] : 0;
    int vB = (t >= off) ? partB[t-off] : 0;
    __syncthreads();
    partA[t] += vA; partB[t] += vB;
    __syncthreads();
  }
  int r  = partA[t] - cA;  // exclusive voxel-rank prefix
  int pb = partB[t] - cB;  // exclusive point prefix
  for (int i = 0; i < 16; ++i) {
    if (flags[i]) {
      rank[base+i] = r;
      pbase[base+i] = pb;
      cvox[b * VOXCAP + r] = t*16 + i;
      ++r;
    }
    pb += cs[i];
  }
}

// -------- counting-sort scatter: sidx = point indices ordered by (batch, voxel) --------
__global__ __launch_bounds__(256) void k_scatter(const int* __restrict__ vid,
                                                 const int* __restrict__ pbase,
                                                 int* __restrict__ cursor,
                                                 int* __restrict__ sidx) {
  int gt = blockIdx.x * 256 + threadIdx.x;
  int b = gt >> 16;
  int idx = b * VOXCAP + vid[gt];
  int pos = pbase[idx] + atomicAdd(&cursor[idx], 1);
  sidx[((size_t)b << 16) + pos] = gt;
}

// -------- fused GEMM (fp32, gathered sorted rows) + BN stats + segmented max pooling --------
// 128 sorted pts x 128 ch per block; sorted order => block-local run-collapse, then one
// atomicMax per (segment, channel) per block (~10M atomics total vs 67M unsorted).
__global__ __launch_bounds__(256) void k_gemm_pool(
    const float* __restrict__ feats, const float* __restrict__ Wg,
    const float* __restrict__ bias,
    const int* __restrict__ vid, const int* __restrict__ rank,
    const int* __restrict__ sidx,
    unsigned int* __restrict__ pool, float* __restrict__ stats, int m)
{
  // overlay: GEMM staging (sF4 2176 + sW4 2048 float4 = 67.6 KB) reused as h[128][128] fp32 (64 KB)
  __shared__ float4 smem4[4224];
  __shared__ int s_sidx[128];
  __shared__ int r_loc[128];
  __shared__ float sh_sum[128], sh_sq[128];
  float4* sF4 = smem4;          // [pt][k/4] padded stride 17
  float4* sW4 = smem4 + 2176;   // [k][c/4] 64x32
  int tid = threadIdx.x;
  int blk = blockIdx.x;
  int b = blk >> 9;             // 512 blocks per batch

  if (tid < 128) {
    int gp = sidx[blk*128 + tid];
    s_sidx[tid] = gp;
    r_loc[tid] = rank[b * VOXCAP + vid[gp]];
    sh_sum[tid] = 0.f; sh_sq[tid] = 0.f;
  }
  __syncthreads();

  const float4* W4 = (const float4*)Wg;
  #pragma unroll
  for (int t = 0; t < 8; ++t) {
    int idx = t*256 + tid;
    sW4[idx] = W4[idx];
    int row = idx >> 4, q = idx & 15;
    const float4* Fr = (const float4*)(feats + (size_t)s_sidx[row] * CIN);
    sF4[row*17 + q] = Fr[q];
  }
  __syncthreads();

  int tp = tid & 15, tc = tid >> 4;
  float acc[8][8];
  #pragma unroll
  for (int i = 0; i < 8; ++i)
    #pragma unroll
    for (int j = 0; j < 8; ++j) acc[i][j] = 0.f;

  for (int k4 = 0; k4 < 16; ++k4) {
    float wlo[4][4], whi[4][4];
    #pragma unroll
    for (int e = 0; e < 4; ++e) {
      float4 t0 = sW4[(4*k4+e)*32 + tc];
      float4 t1 = sW4[(4*k4+e)*32 + 16 + tc];
      wlo[e][0]=t0.x; wlo[e][1]=t0.y; wlo[e][2]=t0.z; wlo[e][3]=t0.w;
      whi[e][0]=t1.x; whi[e][1]=t1.y; whi[e][2]=t1.z; whi[e][3]=t1.w;
    }
    #pragma unroll
    for (int pj = 0; pj < 8; ++pj) {
      int p = (pj < 4) ? (4*tp + pj) : (60 + 4*tp + pj);
      float4 fv = sF4[p*17 + k4];
      float fe[4] = {fv.x, fv.y, fv.z, fv.w};
      #pragma unroll
      for (int e = 0; e < 4; ++e) {
        #pragma unroll
        for (int c = 0; c < 4; ++c) {
          acc[pj][c]   += fe[e] * wlo[e][c];
          acc[pj][4+c] += fe[e] * whi[e][c];
        }
      }
    }
  }

  int clo = 4*tc, chi = 64 + 4*tc;
  float bl[4], bh[4];
  #pragma unroll
  for (int c = 0; c < 4; ++c) { bl[c] = bias[clo+c]; bh[c] = bias[chi+c]; }
  #pragma unroll
  for (int pj = 0; pj < 8; ++pj)
    #pragma unroll
    for (int c = 0; c < 4; ++c) { acc[pj][c] += bl[c]; acc[pj][4+c] += bh[c]; }

  // BN stats partials (raw h)
  #pragma unroll
  for (int c = 0; c < 4; ++c) {
    float s0=0.f, q0=0.f, s1=0.f, q1=0.f;
    #pragma unroll
    for (int pj = 0; pj < 8; ++pj) {
      float a = acc[pj][c], d = acc[pj][4+c];
      s0 += a; q0 += a*a; s1 += d; q1 += d*d;
    }
    atomicAdd(&sh_sum[clo+c], s0); atomicAdd(&sh_sq[clo+c], q0);
    atomicAdd(&sh_sum[chi+c], s1); atomicAdd(&sh_sq[chi+c], q1);
  }

  __syncthreads();               // GEMM reads of sF4/sW4 done; sh_sum complete
  if (tid < 128) {
    atomicAdd(&stats[tid], sh_sum[tid]);
    atomicAdd(&stats[128+tid], sh_sq[tid]);
  }

  // dump h-tile into the (now free) staging LDS: h[p][c], c-major float4
  float4* h4 = smem4;
  #pragma unroll
  for (int pj = 0; pj < 8; ++pj) {
    int p = (pj < 4) ? (4*tp + pj) : (60 + 4*tp + pj);
    h4[p*32 + tc]      = make_float4(acc[pj][0], acc[pj][1], acc[pj][2], acc[pj][3]);
    h4[p*32 + 16 + tc] = make_float4(acc[pj][4], acc[pj][5], acc[pj][6], acc[pj][7]);
  }
  __syncthreads();

  // segmented max: thread = (channel, half); run-collapse equal ranks, one atomic per run
  const float* h = (const float*)smem4;
  int c = tid & 127, half = tid >> 7;
  int p0 = half * 64;
  unsigned int* poolc = pool + (size_t)b * m * COUT + c;
  int curR = r_loc[p0];
  float curV = h[p0*128 + c];
  for (int p = p0 + 1; p < p0 + 64; ++p) {
    int r = r_loc[p];
    float v = h[p*128 + c];
    if (r == curR) { curV = fmaxf(curV, v); }
    else {
      if (curR < m) atomicMax(&poolc[(size_t)curR * COUT], encf(curV));
      curR = r; curV = v;
    }
  }
  if (curR < m) atomicMax(&poolc[(size_t)curR * COUT], encf(curV));
}

// -------- finalize: points mean + BN(affine)+ReLU on pooled maxima (in place) --------
__global__ __launch_bounds__(256) void k_finalize(
    const float* __restrict__ psum, const int* __restrict__ cnt,
    const int* __restrict__ cvox, const float* __restrict__ stats,
    const float* __restrict__ gamma, const float* __restrict__ beta,
    float* __restrict__ out, int m)
{
  int idx = blockIdx.x * 256 + threadIdx.x;
  int npts = BB * m * 3;
  int total = npts + BB * m * COUT;
  if (idx >= total) return;
  if (idx < npts) {
    int b = idx / (m*3); int rem = idx - b*m*3; int r = rem/3, d = rem - 3*r;
    int vox = cvox[b * VOXCAP + r];
    int ii = b * VOXCAP + vox;
    out[idx] = psum[3*ii + d] / (float)cnt[ii];
  } else {
    int c = (idx - npts) & 127;
    float s1 = stats[c], s2 = stats[128+c];
    float mu = s1 / (float)NT;
    float var = s2 / (float)NT - mu*mu;
    float scale = gamma[c] * (1.0f / sqrtf(var + EPSBN));
    float shift = beta[c] - mu * scale;
    float v = decf(__float_as_uint(out[idx]));
    out[idx] = fmaxf(v * scale + shift, 0.f);
  }
}

extern "C" void kernel_launch(void* const* d_in, const int* in_sizes, int n_in,
                              void* d_out, int out_size, void* d_ws, size_t ws_size,
                              hipStream_t stream) {
  const float* xyz   = (const float*)d_in[0];
  const float* feats = (const float*)d_in[1];
  const float* Wg    = (const float*)d_in[2];
  const float* bias  = (const float*)d_in[3];
  const float* gamma = (const float*)d_in[4];
  const float* beta  = (const float*)d_in[5];
  float* out = (float*)d_out;
  int m = out_size / (BB * (3 + COUT));
  if (m <= 0) return;
  int npts = BB * m * 3;
  unsigned int* pool = (unsigned int*)(out + npts);   // pooled-features region of d_out

  char* ws = (char*)d_ws;
  size_t off = 0;
  auto alloc = [&](size_t bytes) { void* p = ws + off; off += (bytes + 255) & ~255ull; return p; };
  unsigned int* mins = (unsigned int*)alloc(BB*3*4);
  size_t zstart = off;
  int*   vmax   = (int*)alloc(BB*3*4);
  int*   cnt    = (int*)alloc((size_t)BB*VOXCAP*4);
  float* psum   = (float*)alloc((size_t)BB*VOXCAP*3*4);
  float* stats  = (float*)alloc(2*COUT*4);
  int*   cursor = (int*)alloc((size_t)BB*VOXCAP*4);
  size_t zend = off;
  int*   vid   = (int*)alloc((size_t)NT*4);
  int*   rank  = (int*)alloc((size_t)BB*VOXCAP*4);
  int*   cvox  = (int*)alloc((size_t)BB*VOXCAP*4);
  int*   pbase = (int*)alloc((size_t)BB*VOXCAP*4);
  int*   sidx  = (int*)alloc((size_t)NT*4);
  if (off > ws_size) return;  // ~8 MB needed; output stays poisoned if insufficient

  hipMemsetAsync(mins, 0x7F, 96, stream);                 // ~3.39e38 per word
  hipMemsetAsync(ws + zstart, 0, zend - zstart, stream);
  hipMemsetAsync(pool, 0, (size_t)BB*m*COUT*4, stream);   // encf(x)>0 ∀x, so 0 = -inf sentinel

  k_min    <<<BB*64, 256, 0, stream>>>(xyz, mins);
  k_vmax   <<<BB*64, 256, 0, stream>>>(xyz, mins, vmax);
  k_vid    <<<NT/256, 256, 0, stream>>>(xyz, mins, vmax, vid, cnt, psum);
  k_scan   <<<BB, 1024, 0, stream>>>(cnt, rank, cvox, pbase);
  k_scatter<<<NT/256, 256, 0, stream>>>(vid, pbase, cursor, sidx);
  k_gemm_pool<<<NT/128, 256, 0, stream>>>(feats, Wg, bias, vid, rank, sidx, pool, stats, m);
  int total = npts + BB*m*COUT;
  k_finalize<<<(total + 255)/256, 256, 0, stream>>>(psum, cnt, cvox, stats, gamma, beta, out, m);
}